// Round 8
// baseline (1026.536 us; speedup 1.0000x reference)
//
#include <hip/hip_runtime.h>

#define TT 1024
#define DD 32
#define HH 64

typedef __fp16 h2v __attribute__((ext_vector_type(2)));
typedef _Float16 f16x8 __attribute__((ext_vector_type(8)));
typedef float f32x4 __attribute__((ext_vector_type(4)));

struct __attribute__((aligned(16))) H4 { h2v p[4]; };

__device__ __forceinline__ h2v pk(float a, float b) {
    return __builtin_amdgcn_cvt_pkrtz(a, b);
}
__device__ __forceinline__ float fsig(float x) {
    float e = __builtin_amdgcn_exp2f(-1.4426950408889634f * x);
    return __builtin_amdgcn_rcpf(1.0f + e);
}
__device__ __forceinline__ float ftanh(float x) {
    float e = __builtin_amdgcn_exp2f(2.885390081777927f * x);
    return 1.0f - 2.0f * __builtin_amdgcn_rcpf(1.0f + e);
}
__device__ __forceinline__ float pick4(f32x4 c, bool s0, bool s1) {
    float lo = s0 ? c[1] : c[0];
    float hi = s0 ? c[3] : c[2];
    return s1 ? hi : lo;
}
__device__ __forceinline__ f16x8 load_afrag(const float* p) {
    float4 f0 = *(const float4*)p;
    float4 f1 = *(const float4*)(p + 4);
    H4 t;
    t.p[0] = pk(f0.x, f0.y); t.p[1] = pk(f0.z, f0.w);
    t.p[2] = pk(f1.x, f1.y); t.p[3] = pk(f1.z, f1.w);
    return __builtin_bit_cast(f16x8, t);
}
#define MFMA16(A, B, C) __builtin_amdgcn_mfma_f32_16x16x32_f16(A, B, C, 0, 0, 0)

__device__ __forceinline__ void mrow(f32x4 (&C)[16], const f16x8 (&A)[16], f16x8 Bv) {
#pragma unroll
    for (int mt = 0; mt < 16; ++mt) C[mt] = MFMA16(A[mt], Bv, C[mt]);
}
__device__ __forceinline__ void mrowz(f32x4 (&C)[16], const f16x8 (&A)[16], f16x8 Bv, f32x4 zv) {
#pragma unroll
    for (int mt = 0; mt < 16; ++mt) C[mt] = MFMA16(A[mt], Bv, zv);
}
// gate-G score for this lane's j: reg select (s0,s1) within frag, frag select
// (s2,s3) across jg. All compile-time register indices.
template<int G>
__device__ __forceinline__ float selg(const f32x4 (&C)[16],
                                      bool s0, bool s1, bool s2, bool s3) {
    float ta = pick4(C[0*4 + G],  s0, s1);
    float tb = pick4(C[1*4 + G],  s0, s1);
    float tc = pick4(C[2*4 + G],  s0, s1);
    float td = pick4(C[3*4 + G],  s0, s1);
    float tl = s2 ? tb : ta;
    float th = s2 ? td : tc;
    return s3 ? th : tl;
}

// ---------------------------------------------------------------------------
// R20: DIFFERENTIAL — self-contained block (no global handoff), same per-wave
// matvec structure as R19 (which failed deterministically at 6.05e-2).
// 256 blocks x 128 threads (2 waves), block = batch b:
//   wave0 = L1: computes h1(i) at iteration i from x(i) (register ring) and
//     h1(i-1) (LDS ring slot (i-1)&1); writes h1(i) to slot i&1.
//   wave1 = L2: one step behind — computes h2(i-1) at iteration i from
//     h1(i-1) (ring slot (i-1)&1, written by wave0 last iteration) and
//     h2(i-2) (wave-private h2buf).
//   __syncthreads() once per iteration (2-wave barrier); every LDS write->read
//   crosses a barrier — no fences, no atomics, no workspace.
// Matvec (identical to R19): m-tile mt = jg*4+g covers gate rows
// g*64+jg*16+m; B columns = batch replicated 16x; lane owns all 4 gate scores
// for j(L) = ((L>>2)&3)*16 + (L>>4)*4 + (L&3) in its own C regs (selg).
// If this passes -> R19's global handoff was the bug. If it fails at the same
// absmax -> the matvec mapping is the bug (bisect next).
// ---------------------------------------------------------------------------
__global__ __launch_bounds__(128, 1) void lstm2_pair(
    const float* __restrict__ x,
    const float* __restrict__ w_ih_l0, const float* __restrict__ w_hh_l0,
    const float* __restrict__ b_ih_l0, const float* __restrict__ b_hh_l0,
    const float* __restrict__ w_ih_l1, const float* __restrict__ w_hh_l1,
    const float* __restrict__ b_ih_l1, const float* __restrict__ b_hh_l1,
    const float* __restrict__ w_fc,   const float* __restrict__ b_fc,
    float* __restrict__ out)
{
    const int b    = blockIdx.x;            // 0..255
    const int tid  = threadIdx.x;
    const int wave = tid >> 6;              // 0 = L1, 1 = L2
    const int lane = tid & 63;
    const int quad = lane >> 4;
    const int mr   = lane & 15;
    const bool s0 = (lane & 1) != 0;
    const bool s1 = (lane & 2) != 0;
    const bool s2 = (lane & 4) != 0;
    const bool s3 = (lane & 8) != 0;
    const int jlane = ((lane >> 2) & 3)*16 + quad*4 + (lane & 3);

    __shared__ __attribute__((aligned(16))) __fp16 h1buf[2][64];
    __shared__ __attribute__((aligned(16))) __fp16 h2buf[64];

    if (tid < 64) {
        h1buf[0][tid] = (__fp16)0.f;        // h1(-1) = 0
        h1buf[1][tid] = (__fp16)0.f;
        h2buf[tid]    = (__fp16)0.f;        // h2(-1) = 0
    }

    // ---- weights (A-operands) + fused biases, per wave role ----
    f16x8 W0[16], W1[16], W2[16], W3[16];
    float bs0, bs1, bs2, bs3;
    if (wave == 0) {
        #pragma unroll
        for (int mt = 0; mt < 16; ++mt) {
            const int G = (mt & 3)*64 + (mt >> 2)*16 + mr;
            W0[mt] = load_afrag(w_ih_l0 + (size_t)G*DD + quad*8);       // x part
            W1[mt] = load_afrag(w_hh_l0 + (size_t)G*HH + quad*8);       // h1 lo
            W2[mt] = load_afrag(w_hh_l0 + (size_t)G*HH + 32 + quad*8);  // h1 hi
            W3[mt] = W0[mt];   // unused on this path
        }
        bs0 = b_ih_l0[0*64 + jlane] + b_hh_l0[0*64 + jlane];
        bs1 = b_ih_l0[1*64 + jlane] + b_hh_l0[1*64 + jlane];
        bs2 = b_ih_l0[2*64 + jlane] + b_hh_l0[2*64 + jlane];
        bs3 = b_ih_l0[3*64 + jlane] + b_hh_l0[3*64 + jlane];
    } else {
        #pragma unroll
        for (int mt = 0; mt < 16; ++mt) {
            const int G = (mt & 3)*64 + (mt >> 2)*16 + mr;
            W0[mt] = load_afrag(w_ih_l1 + (size_t)G*HH + quad*8);       // h1 lo
            W1[mt] = load_afrag(w_ih_l1 + (size_t)G*HH + 32 + quad*8);  // h1 hi
            W2[mt] = load_afrag(w_hh_l1 + (size_t)G*HH + quad*8);       // h2 lo
            W3[mt] = load_afrag(w_hh_l1 + (size_t)G*HH + 32 + quad*8);  // h2 hi
        }
        bs0 = b_ih_l1[0*64 + jlane] + b_hh_l1[0*64 + jlane];
        bs1 = b_ih_l1[1*64 + jlane] + b_hh_l1[1*64 + jlane];
        bs2 = b_ih_l1[2*64 + jlane] + b_hh_l1[2*64 + jlane];
        bs3 = b_ih_l1[3*64 + jlane] + b_hh_l1[3*64 + jlane];
    }

    // x register prefetch ring (wave0 only)
    const float* xrow = x + (size_t)b*(TT*DD) + quad*8;
    float4 xa0 = {0,0,0,0}, xa1 = {0,0,0,0}, xb0 = {0,0,0,0}, xb1 = {0,0,0,0};
    if (wave == 0) {
        xa0 = *(const float4*)(xrow + 0*DD);
        xa1 = *(const float4*)(xrow + 0*DD + 4);
        xb0 = *(const float4*)(xrow + 1*DD);
        xb1 = *(const float4*)(xrow + 1*DD + 4);
    }

    __syncthreads();   // zero-init + weights staged

    const f32x4 zv = {0.f, 0.f, 0.f, 0.f};
    float cst = 0.0f;

#define ACT_H(C)                                                              \
        float Si = selg<0>(C, s0, s1, s2, s3) + bs0;                          \
        float Sf = selg<1>(C, s0, s1, s2, s3) + bs1;                          \
        float Sg = selg<2>(C, s0, s1, s2, s3) + bs2;                          \
        float So = selg<3>(C, s0, s1, s2, s3) + bs3;                          \
        float ii = fsig(Si), ff = fsig(Sf), oo = fsig(So);                    \
        float gg = ftanh(Sg);                                                 \
        cst = ff * cst + ii * gg;                                             \
        float hv = oo * ftanh(cst);

#define STEP(I_, PAR, X0_, X1_)                                               \
    {   const int i = (I_);                                                   \
        if (wave == 0) {                                                      \
            if (i < TT) {                                                     \
                f16x8 Bx; { H4 u;                                             \
                    u.p[0] = pk(X0_.x, X0_.y); u.p[1] = pk(X0_.z, X0_.w);     \
                    u.p[2] = pk(X1_.x, X1_.y); u.p[3] = pk(X1_.z, X1_.w);     \
                    Bx = __builtin_bit_cast(f16x8, u); }                      \
                {   const int tl = (i + 2 < TT) ? (i + 2) : (TT - 1);         \
                    X0_ = *(const float4*)(xrow + (size_t)tl*DD);             \
                    X1_ = *(const float4*)(xrow + (size_t)tl*DD + 4); }       \
                f32x4 C[16];                                                  \
                mrowz(C, W0, Bx, zv);                                         \
                f16x8 D1 = *(const f16x8*)(&h1buf[(PAR)^1][0] + quad*8);      \
                f16x8 D2 = *(const f16x8*)(&h1buf[(PAR)^1][0] + 32 + quad*8); \
                mrow(C, W1, D1);                                              \
                mrow(C, W2, D2);                                              \
                ACT_H(C)                                                      \
                h1buf[PAR][jlane] = (__fp16)hv;                               \
            }                                                                 \
        } else {                                                              \
            if (i >= 1) {                                                     \
                f16x8 B1 = *(const f16x8*)(&h1buf[(PAR)^1][0] + quad*8);      \
                f16x8 B2 = *(const f16x8*)(&h1buf[(PAR)^1][0] + 32 + quad*8); \
                f16x8 D1 = *(const f16x8*)(h2buf + quad*8);                   \
                f16x8 D2 = *(const f16x8*)(h2buf + 32 + quad*8);              \
                f32x4 C[16];                                                  \
                mrowz(C, W0, B1, zv);                                         \
                mrow(C, W1, B2);                                              \
                mrow(C, W2, D1);                                              \
                mrow(C, W3, D2);                                              \
                ACT_H(C)                                                      \
                h2buf[jlane] = (__fp16)hv;                                    \
            }                                                                 \
        }                                                                     \
        __syncthreads();                                                      \
    }

    for (int tb = 0; tb < TT; tb += 2) {
        STEP(tb,     0, xa0, xa1)
        STEP(tb + 1, 1, xb0, xb1)
    }
    STEP(TT, 0, xa0, xa1)   // wave0 idle; wave1 computes h2(TT-1)

#undef STEP
#undef ACT_H

    // FC + sigmoid on h2(TT-1) (in h2buf). Same reduce order as the lineage.
    if (wave == 1) {
        const int jg = lane >> 2;
        float s = 0.f;
        #pragma unroll
        for (int u2 = 0; u2 < 4; ++u2) {
            const int j = jg*4 + u2;
            s += (float)h2buf[j] * w_fc[j];
        }
        s += __shfl_xor(s, 4);
        s += __shfl_xor(s, 8);
        s += __shfl_xor(s, 16);
        s += __shfl_xor(s, 32);
        if (lane == 0) out[b] = fsig(s + b_fc[0]);
    }
}

extern "C" void kernel_launch(void* const* d_in, const int* in_sizes, int n_in,
                              void* d_out, int out_size, void* d_ws, size_t ws_size,
                              hipStream_t stream) {
    lstm2_pair<<<dim3(256), dim3(128), 0, stream>>>(
        (const float*)d_in[0],
        (const float*)d_in[1], (const float*)d_in[2],
        (const float*)d_in[3], (const float*)d_in[4],
        (const float*)d_in[5], (const float*)d_in[6],
        (const float*)d_in[7], (const float*)d_in[8],
        (const float*)d_in[9], (const float*)d_in[10],
        (float*)d_out);
}